// Round 2
// baseline (723.542 us; speedup 1.0000x reference)
//
#include <hip/hip_runtime.h>
#include <hip/hip_bf16.h>

#define INF_F (__builtin_inff())

// ---------------------------------------------------------------------------
// Problem constants: B=4, N=16384, S=4096, D1=128, D2=256, MLP=(256,128)
// M = B*N = 65536 flattened points.
// ---------------------------------------------------------------------------

// points2 [B][256][4096] -> p2t [B][4096][256] (row per source point, for
// coalesced 1KB gather rows in interp)
__global__ __launch_bounds__(256) void transpose_k(const float* __restrict__ in,
                                                   float* __restrict__ out) {
  __shared__ float tile[32][33];
  int b = blockIdx.z;
  int s0 = blockIdx.x * 32;
  int k0 = blockIdx.y * 32;
  int tx = threadIdx.x, ty = threadIdx.y;  // 32 x 8
  const float* src = in + ((size_t)b * 256 + k0) * 4096 + s0;
  for (int r = ty; r < 32; r += 8) tile[r][tx] = src[(size_t)r * 4096 + tx];
  __syncthreads();
  float* dst = out + ((size_t)b * 4096 + s0) * 256 + k0;
  for (int r = ty; r < 32; r += 8) dst[(size_t)r * 256 + tx] = tile[tx][r];
}

__device__ __forceinline__ void top3_insert(float d, int s, float& e0, float& e1,
                                            float& e2, int& j0, int& j1, int& j2) {
  if (d < e2) {
    if (d < e1) {
      e2 = e1; j2 = j1;
      if (d < e0) { e1 = e0; j1 = j0; e0 = d; j0 = s; }
      else        { e1 = d;  j1 = s; }
    } else { e2 = d; j2 = s; }
  }
}

// 3-NN + inverse-distance weights.
// 512 blocks x 512 threads (8 waves). Block = 128 query points of one batch.
// Each thread: 2 queries (lane, lane+64) x 1/8th of S (512 sources).
// Source address is wave-uniform (split = tid>>6) -> pure LDS broadcast.
// 80KB LDS -> 2 blocks/CU -> 16 waves/CU (50% occupancy), 2 indep insert
// chains/thread for ILP.
__global__ __launch_bounds__(512) void knn_k(const float* __restrict__ xyz1,
                                             const float* __restrict__ xyz2,
                                             const int* __restrict__ idx1,
                                             const int* __restrict__ idx2,
                                             int* __restrict__ idx3,
                                             float* __restrict__ wgt) {
  __shared__ float4 sP[4096];  // x,y,z,|p|^2  (64KB)
  __shared__ int sId[4096];    // 16KB
  int bid = blockIdx.x;
  int b = bid >> 7;
  int n0 = (bid & 127) * 128;
  int t = threadIdx.x;
  for (int s = t; s < 4096; s += 512) {
    float x = xyz2[(b * 3 + 0) * 4096 + s];
    float y = xyz2[(b * 3 + 1) * 4096 + s];
    float z = xyz2[(b * 3 + 2) * 4096 + s];
    sP[s] = make_float4(x, y, z, fmaf(x, x, fmaf(y, y, z * z)));
    sId[s] = idx2[b * 4096 + s];
  }
  __syncthreads();
  int lane = t & 63, sp = t >> 6;
  int na = n0 + lane, nb = n0 + lane + 64;
  float pxa = xyz1[(b * 3 + 0) * 16384 + na];
  float pya = xyz1[(b * 3 + 1) * 16384 + na];
  float pza = xyz1[(b * 3 + 2) * 16384 + na];
  float pxb = xyz1[(b * 3 + 0) * 16384 + nb];
  float pyb = xyz1[(b * 3 + 1) * 16384 + nb];
  float pzb = xyz1[(b * 3 + 2) * 16384 + nb];
  int ida = idx1[b * 16384 + na];
  int idb = idx1[b * 16384 + nb];
  float pna = fmaf(pxa, pxa, fmaf(pya, pya, pza * pza));
  float pnb = fmaf(pxb, pxb, fmaf(pyb, pyb, pzb * pzb));
  float e0a = INF_F, e1a = INF_F, e2a = INF_F;
  float e0b = INF_F, e1b = INF_F, e2b = INF_F;
  int j0a = 0, j1a = 0, j2a = 0, j0b = 0, j1b = 0, j2b = 0;
  int sBeg = sp * 512, sEnd = sBeg + 512;
#pragma unroll 4
  for (int s = sBeg; s < sEnd; ++s) {
    float4 p = sP[s];  // wave-uniform addr -> LDS broadcast, conflict-free
    int sid = sId[s];
    float dota = fmaf(pxa, p.x, fmaf(pya, p.y, pza * p.z));
    float dotb = fmaf(pxb, p.x, fmaf(pyb, p.y, pzb * p.z));
    float da = fmaf(-2.f, dota, pna + p.w);  // |a|^2+|b|^2-2ab, as ref
    float db = fmaf(-2.f, dotb, pnb + p.w);
    da = (sid == ida) ? da : INF_F;
    db = (sid == idb) ? db : INF_F;
    top3_insert(da, s, e0a, e1a, e2a, j0a, j1a, j2a);
    top3_insert(db, s, e0b, e1b, e2b, j0b, j1b, j2b);
  }
  __syncthreads();
  // partials: record stride 8 floats, [q 0..127][sp 0..7]: d0 d1 d2 j0 j1 j2
  float* sf = (float*)sP;
  int* si = (int*)sP;
  {
    int ra = (lane * 8 + sp) * 8;
    sf[ra + 0] = e0a; sf[ra + 1] = e1a; sf[ra + 2] = e2a;
    si[ra + 3] = j0a; si[ra + 4] = j1a; si[ra + 5] = j2a;
    int rb = ((lane + 64) * 8 + sp) * 8;
    sf[rb + 0] = e0b; sf[rb + 1] = e1b; sf[rb + 2] = e2b;
    si[rb + 3] = j0b; si[rb + 4] = j1b; si[rb + 5] = j2b;
  }
  __syncthreads();
  if (t < 128) {
    float e0 = INF_F, e1 = INF_F, e2 = INF_F;
    int j0 = 0, j1 = 0, j2 = 0;
    // ascending split order + strict < keeps top_k's lowest-index tie order
    for (int s8 = 0; s8 < 8; ++s8) {
      int r = (t * 8 + s8) * 8;
      for (int q = 0; q < 3; ++q)
        top3_insert(sf[r + q], si[r + 3 + q], e0, e1, e2, j0, j1, j2);
    }
    float r0 = 1.f / (e0 + 1e-8f);
    float r1 = 1.f / (e1 + 1e-8f);
    float r2 = 1.f / (e2 + 1e-8f);
    float rs = r0 + r1 + r2;
    float w0 = r0 / rs, w1 = r1 / rs, w2 = r2 / rs;
    if (e0 > 1e8f) w0 = 0.f;   // ref: where(d3 > BIG, 0, w) + nan_to_num
    if (e1 > 1e8f) w1 = 0.f;
    if (e2 > 1e8f) w2 = 0.f;
    size_t i = (size_t)b * 16384 + n0 + t;
    idx3[i * 3 + 0] = j0; idx3[i * 3 + 1] = j1; idx3[i * 3 + 2] = j2;
    wgt[i * 3 + 0] = w0;  wgt[i * 3 + 1] = w1;  wgt[i * 3 + 2] = w2;
  }
}

// interp[i][k] = sum_j w_j * p2t[b][id_j][k]   (i-major rows of 256 floats)
__global__ __launch_bounds__(256) void interp_k(const float* __restrict__ p2t,
                                                const int* __restrict__ idx3,
                                                const float* __restrict__ wgt,
                                                float* __restrict__ itp) {
  int i0 = blockIdx.x * 128;  // 512 blocks
  int b = i0 >> 14;
  int k = threadIdx.x;
  const float* base = p2t + (size_t)b * 4096 * 256;
#pragma unroll 2
  for (int ii = 0; ii < 128; ++ii) {
    int i = i0 + ii;
    int id0 = idx3[i * 3 + 0], id1 = idx3[i * 3 + 1], id2 = idx3[i * 3 + 2];
    float w0 = wgt[i * 3 + 0], w1v = wgt[i * 3 + 1], w2v = wgt[i * 3 + 2];
    float v = w0 * base[id0 * 256 + k];
    v = fmaf(w1v, base[id1 * 256 + k], v);
    v = fmaf(w2v, base[id2 * 256 + k], v);
    itp[(size_t)i * 256 + k] = v;
  }
}

// GEMM1: h1[c][i] = sum_k w1[c][k] * A[k][i], A = [points1 ; interp], K=384.
// (bias b1 omitted: exactly cancelled by BN mean subtraction)
// 64x64 tile, 4x4 micro, K-chunk 16. grid (1024, 4).
__global__ __launch_bounds__(256) void gemm1_k(const float* __restrict__ p1,
                                               const float* __restrict__ itp,
                                               const float* __restrict__ w1,
                                               float* __restrict__ h1) {
  __shared__ float sW[16][68];  // [kk][cc], pad 68 keeps b128 align, <=2-way banks
  __shared__ float sA[16][68];  // [kk][ii]
  int t = threadIdx.x;
  int i0 = blockIdx.x * 64;
  int c0 = blockIdx.y * 64;
  int b = i0 >> 14;
  int n0 = i0 & 16383;
  int tc = t >> 4, ti = t & 15;
  float acc[4][4] = {{0.f, 0.f, 0.f, 0.f}, {0.f, 0.f, 0.f, 0.f},
                     {0.f, 0.f, 0.f, 0.f}, {0.f, 0.f, 0.f, 0.f}};
  int w_cc = t >> 2, w_k4 = (t & 3) * 4;
  int aA_kk = t >> 4, aA_i4 = (t & 15) * 4;  // k-major source (points1)
  int aB_ii = t >> 2, aB_k4 = (t & 3) * 4;   // i-major source (interp)
  for (int kc = 0; kc < 24; ++kc) {
    int k0 = kc * 16;
    __syncthreads();
    {
      float4 wv = *(const float4*)&w1[(size_t)(c0 + w_cc) * 384 + k0 + w_k4];
      sW[w_k4 + 0][w_cc] = wv.x; sW[w_k4 + 1][w_cc] = wv.y;
      sW[w_k4 + 2][w_cc] = wv.z; sW[w_k4 + 3][w_cc] = wv.w;
    }
    if (k0 < 128) {
      float4 av = *(const float4*)&p1[((size_t)(b * 128 + k0 + aA_kk)) * 16384 + n0 + aA_i4];
      *(float4*)&sA[aA_kk][aA_i4] = av;
    } else {
      float4 av = *(const float4*)&itp[((size_t)(i0 + aB_ii)) * 256 + (k0 - 128) + aB_k4];
      sA[aB_k4 + 0][aB_ii] = av.x; sA[aB_k4 + 1][aB_ii] = av.y;
      sA[aB_k4 + 2][aB_ii] = av.z; sA[aB_k4 + 3][aB_ii] = av.w;
    }
    __syncthreads();
#pragma unroll
    for (int kk = 0; kk < 16; ++kk) {
      float av4[4], wv4[4];
      *(float4*)av4 = *(const float4*)&sA[kk][ti * 4];
      *(float4*)wv4 = *(const float4*)&sW[kk][tc * 4];
#pragma unroll
      for (int a = 0; a < 4; ++a)
#pragma unroll
        for (int q = 0; q < 4; ++q)
          acc[a][q] = fmaf(wv4[a], av4[q], acc[a][q]);
    }
  }
#pragma unroll
  for (int j = 0; j < 4; ++j) {
    int c = c0 + tc * 4 + j;
    float4 o = make_float4(acc[j][0], acc[j][1], acc[j][2], acc[j][3]);
    *(float4*)&h1[(size_t)c * 65536 + i0 + ti * 4] = o;
  }
}

// per-channel BN stats -> fold to a*x + c.  MODE 0: src [C][65536] rows.
// MODE 1: src is d_out [B][128][16384], channel c at 4 strided chunks.
template <int MODE>
__global__ __launch_bounds__(256) void bnstats_k(const float* __restrict__ src,
                                                 const float* __restrict__ gamma,
                                                 const float* __restrict__ beta,
                                                 float* __restrict__ A,
                                                 float* __restrict__ Cc) {
  int c = blockIdx.x;
  int t = threadIdx.x;
  float s1 = 0.f, s2 = 0.f;
  if (MODE == 0) {
    const float* p = src + (size_t)c * 65536;
    for (int e = t * 4; e < 65536; e += 1024) {
      float4 v = *(const float4*)&p[e];
      s1 += (v.x + v.y) + (v.z + v.w);
      s2 += fmaf(v.x, v.x, v.y * v.y) + fmaf(v.z, v.z, v.w * v.w);
    }
  } else {
    for (int bb = 0; bb < 4; ++bb) {
      const float* p = src + ((size_t)(bb * 128 + c)) * 16384;
      for (int e = t * 4; e < 16384; e += 1024) {
        float4 v = *(const float4*)&p[e];
        s1 += (v.x + v.y) + (v.z + v.w);
        s2 += fmaf(v.x, v.x, v.y * v.y) + fmaf(v.z, v.z, v.w * v.w);
      }
    }
  }
  __shared__ float r1[256], r2[256];
  r1[t] = s1; r2[t] = s2;
  __syncthreads();
  for (int off = 128; off > 0; off >>= 1) {
    if (t < off) { r1[t] += r1[t + off]; r2[t] += r2[t + off]; }
    __syncthreads();
  }
  if (t == 0) {
    float mean = r1[0] * (1.f / 65536.f);
    float var = r2[0] * (1.f / 65536.f) - mean * mean;  // biased, as torch BN
    float a = gamma[c] * rsqrtf(var + 1e-5f);
    A[c] = a;
    Cc[c] = beta[c] - mean * a;
  }
}

// GEMM2: out[b][o][n] = sum_c w2[o][c] * relu(a1[c]*h1[c][i]+c1[c]); grid (1024,2)
__global__ __launch_bounds__(256) void gemm2_k(const float* __restrict__ h1,
                                               const float* __restrict__ w2,
                                               const float* __restrict__ a1,
                                               const float* __restrict__ c1,
                                               float* __restrict__ out) {
  __shared__ float sW[16][68];
  __shared__ float sA[16][68];
  int t = threadIdx.x;
  int i0 = blockIdx.x * 64;
  int o0 = blockIdx.y * 64;
  int b = i0 >> 14;
  int n0 = i0 & 16383;
  int tc = t >> 4, ti = t & 15;
  float acc[4][4] = {{0.f, 0.f, 0.f, 0.f}, {0.f, 0.f, 0.f, 0.f},
                     {0.f, 0.f, 0.f, 0.f}, {0.f, 0.f, 0.f, 0.f}};
  int w_cc = t >> 2, w_k4 = (t & 3) * 4;
  int aA_kk = t >> 4, aA_i4 = (t & 15) * 4;
  for (int kc = 0; kc < 16; ++kc) {
    int k0 = kc * 16;
    __syncthreads();
    {
      float4 wv = *(const float4*)&w2[(size_t)(o0 + w_cc) * 256 + k0 + w_k4];
      sW[w_k4 + 0][w_cc] = wv.x; sW[w_k4 + 1][w_cc] = wv.y;
      sW[w_k4 + 2][w_cc] = wv.z; sW[w_k4 + 3][w_cc] = wv.w;
    }
    {
      int c = k0 + aA_kk;
      float sc = a1[c], sh = c1[c];
      float4 hv = *(const float4*)&h1[(size_t)c * 65536 + i0 + aA_i4];
      float4 av;
      av.x = fmaxf(fmaf(sc, hv.x, sh), 0.f);
      av.y = fmaxf(fmaf(sc, hv.y, sh), 0.f);
      av.z = fmaxf(fmaf(sc, hv.z, sh), 0.f);
      av.w = fmaxf(fmaf(sc, hv.w, sh), 0.f);
      *(float4*)&sA[aA_kk][aA_i4] = av;
    }
    __syncthreads();
#pragma unroll
    for (int kk = 0; kk < 16; ++kk) {
      float av4[4], wv4[4];
      *(float4*)av4 = *(const float4*)&sA[kk][ti * 4];
      *(float4*)wv4 = *(const float4*)&sW[kk][tc * 4];
#pragma unroll
      for (int a = 0; a < 4; ++a)
#pragma unroll
        for (int q = 0; q < 4; ++q)
          acc[a][q] = fmaf(wv4[a], av4[q], acc[a][q]);
    }
  }
#pragma unroll
  for (int j = 0; j < 4; ++j) {
    int o = o0 + tc * 4 + j;
    float4 v = make_float4(acc[j][0], acc[j][1], acc[j][2], acc[j][3]);
    *(float4*)&out[((size_t)(b * 128 + o)) * 16384 + n0 + ti * 4] = v;
  }
}

// final in-place BN2 + relu on d_out
__global__ __launch_bounds__(256) void bnapply_k(float* __restrict__ out,
                                                 const float* __restrict__ A,
                                                 const float* __restrict__ Cc) {
  int e4 = blockIdx.x * 256 + threadIdx.x;  // 8192 blocks * 256 = 2M float4s
  int elem = e4 * 4;
  int o = (elem >> 14) & 127;
  float a = A[o], cc = Cc[o];
  float4 v = ((float4*)out)[e4];
  v.x = fmaxf(fmaf(a, v.x, cc), 0.f);
  v.y = fmaxf(fmaf(a, v.y, cc), 0.f);
  v.z = fmaxf(fmaf(a, v.z, cc), 0.f);
  v.w = fmaxf(fmaf(a, v.w, cc), 0.f);
  ((float4*)out)[e4] = v;
}

extern "C" void kernel_launch(void* const* d_in, const int* in_sizes, int n_in,
                              void* d_out, int out_size, void* d_ws, size_t ws_size,
                              hipStream_t stream) {
  const float* xyz1 = (const float*)d_in[0];
  const float* xyz2 = (const float*)d_in[1];
  const float* p1   = (const float*)d_in[2];
  const float* p2   = (const float*)d_in[3];
  const int*   idx1 = (const int*)d_in[4];
  const int*   idx2 = (const int*)d_in[5];
  const float* w1   = (const float*)d_in[6];
  // d_in[7] = b1, d_in[11] = b2: exactly absorbed by BN mean subtraction
  const float* g1   = (const float*)d_in[8];
  const float* be1  = (const float*)d_in[9];
  const float* w2   = (const float*)d_in[10];
  const float* g2   = (const float*)d_in[12];
  const float* be2  = (const float*)d_in[13];
  float* out = (float*)d_out;

  char* ws = (char*)d_ws;
  // layout: idx3 0.75MB | wgt 0.75MB | h1 64MB (p2t 16.8MB aliased: dead
  // before gemm1 writes) | interp 64MB | folded BN params 4KB  => ~135.7MB
  int*   idx3 = (int*)(ws + 0x0);
  float* wgt  = (float*)(ws + 0xC0000);
  float* h1   = (float*)(ws + 0x180000);
  float* p2t  = (float*)(ws + 0x180000);
  float* itp  = (float*)(ws + 0x180000 + 0x4000000);
  float* a1   = (float*)(ws + 0x180000 + 0x8000000);
  float* c1   = a1 + 256;
  float* a2   = c1 + 256;
  float* c2   = a2 + 128;

  hipLaunchKernelGGL(transpose_k, dim3(128, 8, 4), dim3(32, 8), 0, stream, p2, p2t);
  hipLaunchKernelGGL(knn_k, dim3(512), dim3(512), 0, stream,
                     xyz1, xyz2, idx1, idx2, idx3, wgt);
  hipLaunchKernelGGL(interp_k, dim3(512), dim3(256), 0, stream, p2t, idx3, wgt, itp);
  hipLaunchKernelGGL(gemm1_k, dim3(1024, 4), dim3(256), 0, stream, p1, itp, w1, h1);
  hipLaunchKernelGGL((bnstats_k<0>), dim3(256), dim3(256), 0, stream, h1, g1, be1, a1, c1);
  hipLaunchKernelGGL(gemm2_k, dim3(1024, 2), dim3(256), 0, stream, h1, w2, a1, c1, out);
  hipLaunchKernelGGL((bnstats_k<1>), dim3(128), dim3(256), 0, stream, out, g2, be2, a2, c2);
  hipLaunchKernelGGL(bnapply_k, dim3(8192), dim3(256), 0, stream, out, a2, c2);
}

// Round 4
// 466.985 us; speedup vs baseline: 1.5494x; 1.5494x over previous
//
#include <hip/hip_runtime.h>
#include <hip/hip_bf16.h>

#define INF_F (__builtin_inff())

// ---------------------------------------------------------------------------
// Problem constants: B=4, N=16384, S=4096, D1=128, D2=256, MLP=(256,128)
// M = B*N = 65536 flattened points.
// ---------------------------------------------------------------------------

// points2 [B][256][4096] -> p2t [B][4096][256] (row per source point, for
// coalesced 1KB gather rows in interp)
__global__ __launch_bounds__(256) void transpose_k(const float* __restrict__ in,
                                                   float* __restrict__ out) {
  __shared__ float tile[32][33];
  int b = blockIdx.z;
  int s0 = blockIdx.x * 32;
  int k0 = blockIdx.y * 32;
  int tx = threadIdx.x, ty = threadIdx.y;  // 32 x 8
  const float* src = in + ((size_t)b * 256 + k0) * 4096 + s0;
  for (int r = ty; r < 32; r += 8) tile[r][tx] = src[(size_t)r * 4096 + tx];
  __syncthreads();
  float* dst = out + ((size_t)b * 4096 + s0) * 256 + k0;
  for (int r = ty; r < 32; r += 8) dst[(size_t)r * 256 + tx] = tile[tx][r];
}

// 3-NN + inverse-distance weights. Branchless EXACT (dist,idx)-pair top-3:
// 3 v_cmp + 10 v_cndmask per candidate, no exec-mask branches, no key
// truncation (R3 lesson: selection needs exact keys - the output gathers the
// winner's feature row, so a near-tie swap is an O(1) output error).
// 512 blocks x 256 thr; block = 128 queries of one batch; 2 threads/query,
// S staged in 2 chunks of 2048 (40KB LDS -> 4 blocks/CU, 50% occupancy).
// Ascending s + strict < keeps top_k's lowest-index tie order within a
// partition; the 3-entry cross-partition merge compares (d,idx) lexicographic.
__global__ __launch_bounds__(256) void knn_k(const float* __restrict__ xyz1,
                                             const float* __restrict__ xyz2,
                                             const int* __restrict__ idx1,
                                             const int* __restrict__ idx2,
                                             int* __restrict__ idx3,
                                             float* __restrict__ wgt) {
  __shared__ float4 sP[2048];  // x,y,z,|p|^2  (32KB)
  __shared__ int sId[2048];    // 8KB
  int bid = blockIdx.x;
  int b = bid >> 7;
  int n0 = (bid & 127) * 128;
  int t = threadIdx.x;
  int q = t & 127, sp = t >> 7;
  int n = n0 + q;
  float px = xyz1[(b * 3 + 0) * 16384 + n];
  float py = xyz1[(b * 3 + 1) * 16384 + n];
  float pz = xyz1[(b * 3 + 2) * 16384 + n];
  int myid = idx1[b * 16384 + n];
  float pn = fmaf(px, px, fmaf(py, py, pz * pz));
  float e0 = INF_F, e1 = INF_F, e2 = INF_F;
  int j0 = 0, j1 = 0, j2 = 0;
  for (int chunk = 0; chunk < 2; ++chunk) {
    int sbase = chunk << 11;
    __syncthreads();  // protect previous chunk's readers
    for (int s = t; s < 2048; s += 256) {
      float x = xyz2[(b * 3 + 0) * 4096 + sbase + s];
      float y = xyz2[(b * 3 + 1) * 4096 + sbase + s];
      float z = xyz2[(b * 3 + 2) * 4096 + sbase + s];
      sP[s] = make_float4(x, y, z, fmaf(x, x, fmaf(y, y, z * z)));
      sId[s] = idx2[b * 4096 + sbase + s];
    }
    __syncthreads();
    int sBeg = sp << 10, sEnd = sBeg + 1024;
#pragma unroll 8
    for (int s = sBeg; s < sEnd; ++s) {
      float4 p = sP[s];  // wave-uniform addr -> LDS broadcast, conflict-free
      int sid = sId[s];
      float dot = fmaf(px, p.x, fmaf(py, p.y, pz * p.z));
      float d = fmaf(-2.f, dot, pn + p.w);  // ref formula |a|^2+|b|^2-2ab
      d = (sid == myid) ? d : INF_F;
      int sj = sbase + s;
      // branchless sorted top-3 insert, strict < (ascending s => tie keeps
      // earlier index, matching top_k)
      bool l0 = d < e0;
      bool l1 = d < e1;
      bool l2 = d < e2;
      e2 = l1 ? e1 : (l2 ? d : e2);
      j2 = l1 ? j1 : (l2 ? sj : j2);
      e1 = l0 ? e0 : (l1 ? d : e1);
      j1 = l0 ? j0 : (l1 ? sj : j1);
      e0 = l0 ? d : e0;
      j0 = l0 ? sj : j0;
    }
  }
  __syncthreads();
  // sp=1 publishes partials in stride-1 planes [6][128] (conflict-free)
  float* sf = (float*)sP;
  int* si = (int*)sP;
  if (sp == 1) {
    sf[0 * 128 + q] = e0; sf[1 * 128 + q] = e1; sf[2 * 128 + q] = e2;
    si[3 * 128 + q] = j0; si[4 * 128 + q] = j1; si[5 * 128 + q] = j2;
  }
  __syncthreads();
  if (t < 128) {  // sp==0 thread: own regs hold sp0 partial; merge partner's
#pragma unroll
    for (int w = 0; w < 3; ++w) {
      float d = sf[w * 128 + t];
      int sj = si[(w + 3) * 128 + t];
      // lexicographic (d, idx) compare for exact cross-partition tie order
      bool l0 = (d < e0) || (d == e0 && sj < j0);
      bool l1 = (d < e1) || (d == e1 && sj < j1);
      bool l2 = (d < e2) || (d == e2 && sj < j2);
      e2 = l1 ? e1 : (l2 ? d : e2);
      j2 = l1 ? j1 : (l2 ? sj : j2);
      e1 = l0 ? e0 : (l1 ? d : e1);
      j1 = l0 ? j0 : (l1 ? sj : j1);
      e0 = l0 ? d : e0;
      j0 = l0 ? sj : j0;
    }
    float r0 = 1.f / (e0 + 1e-8f);
    float r1 = 1.f / (e1 + 1e-8f);
    float r2 = 1.f / (e2 + 1e-8f);
    float rs = r0 + r1 + r2;
    // guard before divide: if ej<=BIG then rj>0 so rs>0 (no NaN path)
    float w0 = (e0 > 1e8f) ? 0.f : r0 / rs;
    float w1 = (e1 > 1e8f) ? 0.f : r1 / rs;
    float w2 = (e2 > 1e8f) ? 0.f : r2 / rs;
    size_t i = (size_t)b * 16384 + n0 + t;
    idx3[i * 3 + 0] = j0; idx3[i * 3 + 1] = j1; idx3[i * 3 + 2] = j2;
    wgt[i * 3 + 0] = w0;  wgt[i * 3 + 1] = w1;  wgt[i * 3 + 2] = w2;
  }
}

// interp[i][k] = sum_j w_j * p2t[b][id_j][k]   (i-major rows of 256 floats)
__global__ __launch_bounds__(256) void interp_k(const float* __restrict__ p2t,
                                                const int* __restrict__ idx3,
                                                const float* __restrict__ wgt,
                                                float* __restrict__ itp) {
  int i0 = blockIdx.x * 128;  // 512 blocks
  int b = i0 >> 14;
  int k = threadIdx.x;
  const float* base = p2t + (size_t)b * 4096 * 256;
#pragma unroll 2
  for (int ii = 0; ii < 128; ++ii) {
    int i = i0 + ii;
    int id0 = idx3[i * 3 + 0], id1 = idx3[i * 3 + 1], id2 = idx3[i * 3 + 2];
    float w0 = wgt[i * 3 + 0], w1v = wgt[i * 3 + 1], w2v = wgt[i * 3 + 2];
    float v = w0 * base[id0 * 256 + k];
    v = fmaf(w1v, base[id1 * 256 + k], v);
    v = fmaf(w2v, base[id2 * 256 + k], v);
    itp[(size_t)i * 256 + k] = v;
  }
}

// GEMM1: h1[c][i] = sum_k w1[c][k] * A[k][i], A = [points1 ; interp], K=384.
// (bias b1 omitted: exactly cancelled by BN mean subtraction)
// 64x64 tile, 4x4 micro, K-chunk 16. grid (1024, 4).
__global__ __launch_bounds__(256) void gemm1_k(const float* __restrict__ p1,
                                               const float* __restrict__ itp,
                                               const float* __restrict__ w1,
                                               float* __restrict__ h1) {
  __shared__ float sW[16][68];  // [kk][cc], pad 68 keeps b128 align, <=2-way banks
  __shared__ float sA[16][68];  // [kk][ii]
  int t = threadIdx.x;
  int i0 = blockIdx.x * 64;
  int c0 = blockIdx.y * 64;
  int b = i0 >> 14;
  int n0 = i0 & 16383;
  int tc = t >> 4, ti = t & 15;
  float acc[4][4] = {{0.f, 0.f, 0.f, 0.f}, {0.f, 0.f, 0.f, 0.f},
                     {0.f, 0.f, 0.f, 0.f}, {0.f, 0.f, 0.f, 0.f}};
  int w_cc = t >> 2, w_k4 = (t & 3) * 4;
  int aA_kk = t >> 4, aA_i4 = (t & 15) * 4;  // k-major source (points1)
  int aB_ii = t >> 2, aB_k4 = (t & 3) * 4;   // i-major source (interp)
  for (int kc = 0; kc < 24; ++kc) {
    int k0 = kc * 16;
    __syncthreads();
    {
      float4 wv = *(const float4*)&w1[(size_t)(c0 + w_cc) * 384 + k0 + w_k4];
      sW[w_k4 + 0][w_cc] = wv.x; sW[w_k4 + 1][w_cc] = wv.y;
      sW[w_k4 + 2][w_cc] = wv.z; sW[w_k4 + 3][w_cc] = wv.w;
    }
    if (k0 < 128) {
      float4 av = *(const float4*)&p1[((size_t)(b * 128 + k0 + aA_kk)) * 16384 + n0 + aA_i4];
      *(float4*)&sA[aA_kk][aA_i4] = av;
    } else {
      float4 av = *(const float4*)&itp[((size_t)(i0 + aB_ii)) * 256 + (k0 - 128) + aB_k4];
      sA[aB_k4 + 0][aB_ii] = av.x; sA[aB_k4 + 1][aB_ii] = av.y;
      sA[aB_k4 + 2][aB_ii] = av.z; sA[aB_k4 + 3][aB_ii] = av.w;
    }
    __syncthreads();
#pragma unroll
    for (int kk = 0; kk < 16; ++kk) {
      float av4[4], wv4[4];
      *(float4*)av4 = *(const float4*)&sA[kk][ti * 4];
      *(float4*)wv4 = *(const float4*)&sW[kk][tc * 4];
#pragma unroll
      for (int a = 0; a < 4; ++a)
#pragma unroll
        for (int q = 0; q < 4; ++q)
          acc[a][q] = fmaf(wv4[a], av4[q], acc[a][q]);
    }
  }
#pragma unroll
  for (int j = 0; j < 4; ++j) {
    int c = c0 + tc * 4 + j;
    float4 o = make_float4(acc[j][0], acc[j][1], acc[j][2], acc[j][3]);
    *(float4*)&h1[(size_t)c * 65536 + i0 + ti * 4] = o;
  }
}

// per-channel BN stats -> fold to a*x + c.  MODE 0: src [C][65536] rows.
// MODE 1: src is d_out [B][128][16384], channel c at 4 strided chunks.
template <int MODE>
__global__ __launch_bounds__(256) void bnstats_k(const float* __restrict__ src,
                                                 const float* __restrict__ gamma,
                                                 const float* __restrict__ beta,
                                                 float* __restrict__ A,
                                                 float* __restrict__ Cc) {
  int c = blockIdx.x;
  int t = threadIdx.x;
  float s1 = 0.f, s2 = 0.f;
  if (MODE == 0) {
    const float* p = src + (size_t)c * 65536;
    for (int e = t * 4; e < 65536; e += 1024) {
      float4 v = *(const float4*)&p[e];
      s1 += (v.x + v.y) + (v.z + v.w);
      s2 += fmaf(v.x, v.x, v.y * v.y) + fmaf(v.z, v.z, v.w * v.w);
    }
  } else {
    for (int bb = 0; bb < 4; ++bb) {
      const float* p = src + ((size_t)(bb * 128 + c)) * 16384;
      for (int e = t * 4; e < 16384; e += 1024) {
        float4 v = *(const float4*)&p[e];
        s1 += (v.x + v.y) + (v.z + v.w);
        s2 += fmaf(v.x, v.x, v.y * v.y) + fmaf(v.z, v.z, v.w * v.w);
      }
    }
  }
  __shared__ float r1[256], r2[256];
  r1[t] = s1; r2[t] = s2;
  __syncthreads();
  for (int off = 128; off > 0; off >>= 1) {
    if (t < off) { r1[t] += r1[t + off]; r2[t] += r2[t + off]; }
    __syncthreads();
  }
  if (t == 0) {
    float mean = r1[0] * (1.f / 65536.f);
    float var = r2[0] * (1.f / 65536.f) - mean * mean;  // biased, as torch BN
    float a = gamma[c] * rsqrtf(var + 1e-5f);
    A[c] = a;
    Cc[c] = beta[c] - mean * a;
  }
}

// GEMM2: out[b][o][n] = sum_c w2[o][c] * relu(a1[c]*h1[c][i]+c1[c]); grid (1024,2)
__global__ __launch_bounds__(256) void gemm2_k(const float* __restrict__ h1,
                                               const float* __restrict__ w2,
                                               const float* __restrict__ a1,
                                               const float* __restrict__ c1,
                                               float* __restrict__ out) {
  __shared__ float sW[16][68];
  __shared__ float sA[16][68];
  int t = threadIdx.x;
  int i0 = blockIdx.x * 64;
  int o0 = blockIdx.y * 64;
  int b = i0 >> 14;
  int n0 = i0 & 16383;
  int tc = t >> 4, ti = t & 15;
  float acc[4][4] = {{0.f, 0.f, 0.f, 0.f}, {0.f, 0.f, 0.f, 0.f},
                     {0.f, 0.f, 0.f, 0.f}, {0.f, 0.f, 0.f, 0.f}};
  int w_cc = t >> 2, w_k4 = (t & 3) * 4;
  int aA_kk = t >> 4, aA_i4 = (t & 15) * 4;
  for (int kc = 0; kc < 16; ++kc) {
    int k0 = kc * 16;
    __syncthreads();
    {
      float4 wv = *(const float4*)&w2[(size_t)(o0 + w_cc) * 256 + k0 + w_k4];
      sW[w_k4 + 0][w_cc] = wv.x; sW[w_k4 + 1][w_cc] = wv.y;
      sW[w_k4 + 2][w_cc] = wv.z; sW[w_k4 + 3][w_cc] = wv.w;
    }
    {
      int c = k0 + aA_kk;
      float sc = a1[c], sh = c1[c];
      float4 hv = *(const float4*)&h1[(size_t)c * 65536 + i0 + aA_i4];
      float4 av;
      av.x = fmaxf(fmaf(sc, hv.x, sh), 0.f);
      av.y = fmaxf(fmaf(sc, hv.y, sh), 0.f);
      av.z = fmaxf(fmaf(sc, hv.z, sh), 0.f);
      av.w = fmaxf(fmaf(sc, hv.w, sh), 0.f);
      *(float4*)&sA[aA_kk][aA_i4] = av;
    }
    __syncthreads();
#pragma unroll
    for (int kk = 0; kk < 16; ++kk) {
      float av4[4], wv4[4];
      *(float4*)av4 = *(const float4*)&sA[kk][ti * 4];
      *(float4*)wv4 = *(const float4*)&sW[kk][tc * 4];
#pragma unroll
      for (int a = 0; a < 4; ++a)
#pragma unroll
        for (int q = 0; q < 4; ++q)
          acc[a][q] = fmaf(wv4[a], av4[q], acc[a][q]);
    }
  }
#pragma unroll
  for (int j = 0; j < 4; ++j) {
    int o = o0 + tc * 4 + j;
    float4 v = make_float4(acc[j][0], acc[j][1], acc[j][2], acc[j][3]);
    *(float4*)&out[((size_t)(b * 128 + o)) * 16384 + n0 + ti * 4] = v;
  }
}

// final in-place BN2 + relu on d_out
__global__ __launch_bounds__(256) void bnapply_k(float* __restrict__ out,
                                                 const float* __restrict__ A,
                                                 const float* __restrict__ Cc) {
  int e4 = blockIdx.x * 256 + threadIdx.x;  // 8192 blocks * 256 = 2M float4s
  int elem = e4 * 4;
  int o = (elem >> 14) & 127;
  float a = A[o], cc = Cc[o];
  float4 v = ((float4*)out)[e4];
  v.x = fmaxf(fmaf(a, v.x, cc), 0.f);
  v.y = fmaxf(fmaf(a, v.y, cc), 0.f);
  v.z = fmaxf(fmaf(a, v.z, cc), 0.f);
  v.w = fmaxf(fmaf(a, v.w, cc), 0.f);
  ((float4*)out)[e4] = v;
}

extern "C" void kernel_launch(void* const* d_in, const int* in_sizes, int n_in,
                              void* d_out, int out_size, void* d_ws, size_t ws_size,
                              hipStream_t stream) {
  const float* xyz1 = (const float*)d_in[0];
  const float* xyz2 = (const float*)d_in[1];
  const float* p1   = (const float*)d_in[2];
  const float* p2   = (const float*)d_in[3];
  const int*   idx1 = (const int*)d_in[4];
  const int*   idx2 = (const int*)d_in[5];
  const float* w1   = (const float*)d_in[6];
  // d_in[7] = b1, d_in[11] = b2: exactly absorbed by BN mean subtraction
  const float* g1   = (const float*)d_in[8];
  const float* be1  = (const float*)d_in[9];
  const float* w2   = (const float*)d_in[10];
  const float* g2   = (const float*)d_in[12];
  const float* be2  = (const float*)d_in[13];
  float* out = (float*)d_out;

  char* ws = (char*)d_ws;
  // layout: idx3 0.75MB | wgt 0.75MB | h1 64MB (p2t 16.8MB aliased: dead
  // before gemm1 writes) | interp 64MB | folded BN params 4KB  => ~135.7MB
  int*   idx3 = (int*)(ws + 0x0);
  float* wgt  = (float*)(ws + 0xC0000);
  float* h1   = (float*)(ws + 0x180000);
  float* p2t  = (float*)(ws + 0x180000);
  float* itp  = (float*)(ws + 0x180000 + 0x4000000);
  float* a1   = (float*)(ws + 0x180000 + 0x8000000);
  float* c1   = a1 + 256;
  float* a2   = c1 + 256;
  float* c2   = a2 + 128;

  hipLaunchKernelGGL(transpose_k, dim3(128, 8, 4), dim3(32, 8), 0, stream, p2, p2t);
  hipLaunchKernelGGL(knn_k, dim3(512), dim3(256), 0, stream,
                     xyz1, xyz2, idx1, idx2, idx3, wgt);
  hipLaunchKernelGGL(interp_k, dim3(512), dim3(256), 0, stream, p2t, idx3, wgt, itp);
  hipLaunchKernelGGL(gemm1_k, dim3(1024, 4), dim3(256), 0, stream, p1, itp, w1, h1);
  hipLaunchKernelGGL((bnstats_k<0>), dim3(256), dim3(256), 0, stream, h1, g1, be1, a1, c1);
  hipLaunchKernelGGL(gemm2_k, dim3(1024, 2), dim3(256), 0, stream, h1, w2, a1, c1, out);
  hipLaunchKernelGGL((bnstats_k<1>), dim3(128), dim3(256), 0, stream, out, g2, be2, a2, c2);
  hipLaunchKernelGGL(bnapply_k, dim3(8192), dim3(256), 0, stream, out, a2, c2);
}

// Round 5
// 311.190 us; speedup vs baseline: 2.3251x; 1.5006x over previous
//
#include <hip/hip_runtime.h>
#include <hip/hip_bf16.h>

#define INF_F (__builtin_inff())

typedef __attribute__((ext_vector_type(8))) short bf16x8;
typedef __attribute__((ext_vector_type(4))) float f32x4;

__device__ __forceinline__ unsigned short f2bf(float f) {
  __hip_bfloat16 h = __float2bfloat16(f);
  return __builtin_bit_cast(unsigned short, h);
}
__device__ __forceinline__ float bf2f(unsigned short u) {
  return __uint_as_float((unsigned)u << 16);
}

// ---------------------------------------------------------------------------
// B=4, N=16384, S=4096, D1=128, D2=256, MLP=(256,128). M = B*N = 65536.
// Activations X: [65536][384] bf16 (cols 0..127 = points1^T, 128..383 = interp)
// h1T: [65536][256] bf16 ; out2T: [65536][128] fp32.
// GEMMs: D[c][n] = W[c][k] * X[n][k] via mfma_f32_16x16x32_bf16,
//   A-operand = W ([c][k] natural row-major), B-operand = X ([n][k] row-major).
//   C/D map (HW-verified): col=lane&15, row=(lane>>4)*4+reg.
// ---------------------------------------------------------------------------

// points2 [B][256][4096] -> p2t [B][4096][256] fp32 (coalesced gather rows)
__global__ __launch_bounds__(256) void transpose_k(const float* __restrict__ in,
                                                   float* __restrict__ out) {
  __shared__ float tile[32][33];
  int b = blockIdx.z;
  int s0 = blockIdx.x * 32;
  int k0 = blockIdx.y * 32;
  int tx = threadIdx.x, ty = threadIdx.y;  // 32 x 8
  const float* src = in + ((size_t)b * 256 + k0) * 4096 + s0;
  for (int r = ty; r < 32; r += 8) tile[r][tx] = src[(size_t)r * 4096 + tx];
  __syncthreads();
  float* dst = out + ((size_t)b * 4096 + s0) * 256 + k0;
  for (int r = ty; r < 32; r += 8) dst[(size_t)r * 256 + tx] = tile[tx][r];
}

// p1 [B][128][16384] fp32 -> X[b*16384+n][0..127] bf16 (transposed)
__global__ __launch_bounds__(256) void p1t_k(const float* __restrict__ p1,
                                             unsigned short* __restrict__ X) {
  __shared__ float tile[32][33];
  int b = blockIdx.z;
  int n0 = blockIdx.x * 32;
  int c0 = blockIdx.y * 32;
  int tx = threadIdx.x, ty = threadIdx.y;
  const float* src = p1 + ((size_t)b * 128 + c0) * 16384 + n0;
  for (int r = ty; r < 32; r += 8) tile[r][tx] = src[(size_t)r * 16384 + tx];
  __syncthreads();
  for (int r = ty; r < 32; r += 8)
    X[((size_t)(b * 16384 + n0 + r)) * 384 + c0 + tx] = f2bf(tile[tx][r]);
}

// w1 [256][384], w2 [128][256] fp32 -> bf16 copies (same layout)
__global__ __launch_bounds__(256) void wcvt_k(const float* __restrict__ w1,
                                              const float* __restrict__ w2,
                                              unsigned short* __restrict__ w1b,
                                              unsigned short* __restrict__ w2b) {
  int id = blockIdx.x * 256 + threadIdx.x;  // 512 blocks = 131072 = 98304+32768
  if (id < 98304) w1b[id] = f2bf(w1[id]);
  else w2b[id - 98304] = f2bf(w2[id - 98304]);
}

// 3-NN + inverse-distance weights (unchanged from R4: branchless exact pairs)
__global__ __launch_bounds__(256) void knn_k(const float* __restrict__ xyz1,
                                             const float* __restrict__ xyz2,
                                             const int* __restrict__ idx1,
                                             const int* __restrict__ idx2,
                                             int* __restrict__ idx3,
                                             float* __restrict__ wgt) {
  __shared__ float4 sP[2048];
  __shared__ int sId[2048];
  int bid = blockIdx.x;
  int b = bid >> 7;
  int n0 = (bid & 127) * 128;
  int t = threadIdx.x;
  int q = t & 127, sp = t >> 7;
  int n = n0 + q;
  float px = xyz1[(b * 3 + 0) * 16384 + n];
  float py = xyz1[(b * 3 + 1) * 16384 + n];
  float pz = xyz1[(b * 3 + 2) * 16384 + n];
  int myid = idx1[b * 16384 + n];
  float pn = fmaf(px, px, fmaf(py, py, pz * pz));
  float e0 = INF_F, e1 = INF_F, e2 = INF_F;
  int j0 = 0, j1 = 0, j2 = 0;
  for (int chunk = 0; chunk < 2; ++chunk) {
    int sbase = chunk << 11;
    __syncthreads();
    for (int s = t; s < 2048; s += 256) {
      float x = xyz2[(b * 3 + 0) * 4096 + sbase + s];
      float y = xyz2[(b * 3 + 1) * 4096 + sbase + s];
      float z = xyz2[(b * 3 + 2) * 4096 + sbase + s];
      sP[s] = make_float4(x, y, z, fmaf(x, x, fmaf(y, y, z * z)));
      sId[s] = idx2[b * 4096 + sbase + s];
    }
    __syncthreads();
    int sBeg = sp << 10, sEnd = sBeg + 1024;
#pragma unroll 8
    for (int s = sBeg; s < sEnd; ++s) {
      float4 p = sP[s];
      int sid = sId[s];
      float dot = fmaf(px, p.x, fmaf(py, p.y, pz * p.z));
      float d = fmaf(-2.f, dot, pn + p.w);
      d = (sid == myid) ? d : INF_F;
      int sj = sbase + s;
      bool l0 = d < e0;
      bool l1 = d < e1;
      bool l2 = d < e2;
      e2 = l1 ? e1 : (l2 ? d : e2);
      j2 = l1 ? j1 : (l2 ? sj : j2);
      e1 = l0 ? e0 : (l1 ? d : e1);
      j1 = l0 ? j0 : (l1 ? sj : j1);
      e0 = l0 ? d : e0;
      j0 = l0 ? sj : j0;
    }
  }
  __syncthreads();
  float* sf = (float*)sP;
  int* si = (int*)sP;
  if (sp == 1) {
    sf[0 * 128 + q] = e0; sf[1 * 128 + q] = e1; sf[2 * 128 + q] = e2;
    si[3 * 128 + q] = j0; si[4 * 128 + q] = j1; si[5 * 128 + q] = j2;
  }
  __syncthreads();
  if (t < 128) {
#pragma unroll
    for (int w = 0; w < 3; ++w) {
      float d = sf[w * 128 + t];
      int sj = si[(w + 3) * 128 + t];
      bool l0 = (d < e0) || (d == e0 && sj < j0);
      bool l1 = (d < e1) || (d == e1 && sj < j1);
      bool l2 = (d < e2) || (d == e2 && sj < j2);
      e2 = l1 ? e1 : (l2 ? d : e2);
      j2 = l1 ? j1 : (l2 ? sj : j2);
      e1 = l0 ? e0 : (l1 ? d : e1);
      j1 = l0 ? j0 : (l1 ? sj : j1);
      e0 = l0 ? d : e0;
      j0 = l0 ? sj : j0;
    }
    float r0 = 1.f / (e0 + 1e-8f);
    float r1 = 1.f / (e1 + 1e-8f);
    float r2 = 1.f / (e2 + 1e-8f);
    float rs = r0 + r1 + r2;
    float w0 = (e0 > 1e8f) ? 0.f : r0 / rs;
    float w1 = (e1 > 1e8f) ? 0.f : r1 / rs;
    float w2 = (e2 > 1e8f) ? 0.f : r2 / rs;
    size_t i = (size_t)b * 16384 + n0 + t;
    idx3[i * 3 + 0] = j0; idx3[i * 3 + 1] = j1; idx3[i * 3 + 2] = j2;
    wgt[i * 3 + 0] = w0;  wgt[i * 3 + 1] = w1;  wgt[i * 3 + 2] = w2;
  }
}

// interp -> X[i][128+k] bf16
__global__ __launch_bounds__(256) void interp_k(const float* __restrict__ p2t,
                                                const int* __restrict__ idx3,
                                                const float* __restrict__ wgt,
                                                unsigned short* __restrict__ X) {
  int i0 = blockIdx.x * 128;
  int b = i0 >> 14;
  int k = threadIdx.x;
  const float* base = p2t + (size_t)b * 4096 * 256;
#pragma unroll 2
  for (int ii = 0; ii < 128; ++ii) {
    int i = i0 + ii;
    int id0 = idx3[i * 3 + 0], id1 = idx3[i * 3 + 1], id2 = idx3[i * 3 + 2];
    float w0 = wgt[i * 3 + 0], w1v = wgt[i * 3 + 1], w2v = wgt[i * 3 + 2];
    float v = w0 * base[id0 * 256 + k];
    v = fmaf(w1v, base[id1 * 256 + k], v);
    v = fmaf(w2v, base[id2 * 256 + k], v);
    X[(size_t)i * 384 + 128 + k] = f2bf(v);
  }
}

// GEMM1 (MFMA): h1T[n][c] = sum_k w1[c][k] X[n][k].  Tile 128c x 128n,
// 4 waves of 64c x 64n, BK=32, K=384. grid (512, 2).
__global__ __launch_bounds__(256) void gemm1_k(const unsigned short* __restrict__ X,
                                               const unsigned short* __restrict__ Wb,
                                               unsigned short* __restrict__ h1T) {
  __shared__ unsigned short sW[128][40];  // pad 40: 80B rows, b128-aligned, spread banks
  __shared__ unsigned short sX[128][40];
  int t = threadIdx.x;
  int i0 = blockIdx.x * 128;
  int c0 = blockIdx.y * 128;
  int w = t >> 6, lane = t & 63;
  int wc = (w & 1) * 64, wn = (w >> 1) * 64;
  int l15 = lane & 15, g = lane >> 4;
  f32x4 acc[4][4];
#pragma unroll
  for (int a = 0; a < 4; ++a)
#pragma unroll
    for (int bq = 0; bq < 4; ++bq) acc[a][bq] = (f32x4)0.f;
  int sr = t & 127, sh = t >> 7;
  for (int kc = 0; kc < 12; ++kc) {
    int k0 = kc * 32;
    __syncthreads();
    {
      const uint4* gw = (const uint4*)&Wb[(size_t)(c0 + sr) * 384 + k0 + sh * 16];
      uint4 v0 = gw[0], v1 = gw[1];
      *(uint4*)&sW[sr][sh * 16] = v0;
      *(uint4*)&sW[sr][sh * 16 + 8] = v1;
      const uint4* gx = (const uint4*)&X[(size_t)(i0 + sr) * 384 + k0 + sh * 16];
      uint4 x0 = gx[0], x1 = gx[1];
      *(uint4*)&sX[sr][sh * 16] = x0;
      *(uint4*)&sX[sr][sh * 16 + 8] = x1;
    }
    __syncthreads();
    bf16x8 a[4], b[4];
#pragma unroll
    for (int tm = 0; tm < 4; ++tm)
      a[tm] = *(const bf16x8*)&sW[wc + tm * 16 + l15][g * 8];
#pragma unroll
    for (int tn = 0; tn < 4; ++tn)
      b[tn] = *(const bf16x8*)&sX[wn + tn * 16 + l15][g * 8];
#pragma unroll
    for (int tm = 0; tm < 4; ++tm)
#pragma unroll
      for (int tn = 0; tn < 4; ++tn)
        acc[tm][tn] = __builtin_amdgcn_mfma_f32_16x16x32_bf16(a[tm], b[tn], acc[tm][tn], 0, 0, 0);
  }
#pragma unroll
  for (int tm = 0; tm < 4; ++tm)
#pragma unroll
    for (int tn = 0; tn < 4; ++tn) {
      int c = c0 + wc + tm * 16 + g * 4;       // 4 consecutive c = regs
      int n = i0 + wn + tn * 16 + l15;
      f32x4 v = acc[tm][tn];
      ushort4 o;
      o.x = f2bf(v[0]); o.y = f2bf(v[1]); o.z = f2bf(v[2]); o.w = f2bf(v[3]);
      *(ushort4*)&h1T[(size_t)n * 256 + c] = o;
    }
}

// BN1 stats over h1T bf16 [65536][256]: 256 blocks x 256 rows
__global__ __launch_bounds__(256) void bnstats1_k(const unsigned short* __restrict__ h,
                                                  float* __restrict__ part) {
  int t = threadIdx.x, q = t & 63, ro = t >> 6;
  int r0 = blockIdx.x * 256;
  float s0 = 0, s1 = 0, s2 = 0, s3 = 0, q0 = 0, q1 = 0, q2 = 0, q3 = 0;
  for (int it = 0; it < 64; ++it) {
    size_t r = r0 + it * 4 + ro;
    ushort4 v = *(const ushort4*)&h[r * 256 + q * 4];
    float f0 = bf2f(v.x), f1 = bf2f(v.y), f2 = bf2f(v.z), f3 = bf2f(v.w);
    s0 += f0; q0 += f0 * f0;
    s1 += f1; q1 += f1 * f1;
    s2 += f2; q2 += f2 * f2;
    s3 += f3; q3 += f3 * f3;
  }
  __shared__ float sm[256][8];
  sm[t][0] = s0; sm[t][1] = s1; sm[t][2] = s2; sm[t][3] = s3;
  sm[t][4] = q0; sm[t][5] = q1; sm[t][6] = q2; sm[t][7] = q3;
  __syncthreads();
  if (t < 64) {
#pragma unroll
    for (int j = 1; j < 4; ++j)
#pragma unroll
      for (int e = 0; e < 8; ++e) sm[t][e] += sm[t + 64 * j][e];
#pragma unroll
    for (int i = 0; i < 4; ++i) {
      part[((size_t)blockIdx.x * 256 + t * 4 + i) * 2 + 0] = sm[t][i];
      part[((size_t)blockIdx.x * 256 + t * 4 + i) * 2 + 1] = sm[t][4 + i];
    }
  }
}

// BN2 stats over out2T fp32 [65536][128]: 256 blocks x 256 rows
__global__ __launch_bounds__(256) void bnstats2_k(const float* __restrict__ o2,
                                                  float* __restrict__ part) {
  int t = threadIdx.x, q = t & 31, ro = t >> 5;
  int r0 = blockIdx.x * 256;
  float s0 = 0, s1 = 0, s2 = 0, s3 = 0, q0 = 0, q1 = 0, q2 = 0, q3 = 0;
  for (int it = 0; it < 32; ++it) {
    size_t r = r0 + it * 8 + ro;
    float4 v = *(const float4*)&o2[r * 128 + q * 4];
    s0 += v.x; q0 += v.x * v.x;
    s1 += v.y; q1 += v.y * v.y;
    s2 += v.z; q2 += v.z * v.z;
    s3 += v.w; q3 += v.w * v.w;
  }
  __shared__ float sm[256][8];
  sm[t][0] = s0; sm[t][1] = s1; sm[t][2] = s2; sm[t][3] = s3;
  sm[t][4] = q0; sm[t][5] = q1; sm[t][6] = q2; sm[t][7] = q3;
  __syncthreads();
  if (t < 32) {
#pragma unroll
    for (int j = 1; j < 8; ++j)
#pragma unroll
      for (int e = 0; e < 8; ++e) sm[t][e] += sm[t + 32 * j][e];
#pragma unroll
    for (int i = 0; i < 4; ++i) {
      part[((size_t)blockIdx.x * 128 + t * 4 + i) * 2 + 0] = sm[t][i];
      part[((size_t)blockIdx.x * 128 + t * 4 + i) * 2 + 1] = sm[t][4 + i];
    }
  }
}

// fold partials -> per-channel a*x + c
template <int C>
__global__ __launch_bounds__(256) void bnfold_k(const float* __restrict__ part,
                                                const float* __restrict__ g,
                                                const float* __restrict__ be,
                                                float* __restrict__ A,
                                                float* __restrict__ Cc) {
  int c = threadIdx.x;
  if (c >= C) return;
  float s1 = 0.f, s2 = 0.f;
  for (int b = 0; b < 256; ++b) {
    s1 += part[((size_t)b * C + c) * 2 + 0];
    s2 += part[((size_t)b * C + c) * 2 + 1];
  }
  float mean = s1 * (1.f / 65536.f);
  float var = s2 * (1.f / 65536.f) - mean * mean;  // biased, as torch BN
  float a = g[c] * rsqrtf(var + 1e-5f);
  A[c] = a;
  Cc[c] = be[c] - mean * a;
}

// h1bn[i][c] = bf16(relu(a1[c]*h1T[i][c] + c1[c])): 8192 blocks x 256, 8 elem/thr
__global__ __launch_bounds__(256) void bnapply1_k(const unsigned short* __restrict__ h,
                                                  const float* __restrict__ A,
                                                  const float* __restrict__ C,
                                                  unsigned short* __restrict__ o) {
  size_t idx = ((size_t)blockIdx.x * 256 + threadIdx.x) * 8;
  int c = (int)(idx & 255);
  uint4 v = *(const uint4*)&h[idx];
  float4 a0 = *(const float4*)&A[c], a1 = *(const float4*)&A[c + 4];
  float4 c0 = *(const float4*)&C[c], c1 = *(const float4*)&C[c + 4];
  unsigned r[4] = {v.x, v.y, v.z, v.w};
  float av[8] = {a0.x, a0.y, a0.z, a0.w, a1.x, a1.y, a1.z, a1.w};
  float cv[8] = {c0.x, c0.y, c0.z, c0.w, c1.x, c1.y, c1.z, c1.w};
  unsigned w[4];
#pragma unroll
  for (int e = 0; e < 4; ++e) {
    float f0 = bf2f((unsigned short)(r[e] & 0xFFFFu));
    float f1 = bf2f((unsigned short)(r[e] >> 16));
    f0 = fmaxf(fmaf(av[2 * e], f0, cv[2 * e]), 0.f);
    f1 = fmaxf(fmaf(av[2 * e + 1], f1, cv[2 * e + 1]), 0.f);
    w[e] = (unsigned)f2bf(f0) | ((unsigned)f2bf(f1) << 16);
  }
  uint4 ov = {w[0], w[1], w[2], w[3]};
  *(uint4*)&o[idx] = ov;
}

// GEMM2 (MFMA): out2T[n][c2] = sum_k w2[c2][k] h1bn[n][k]. Tile 128x128,
// K=256. grid (512).
__global__ __launch_bounds__(256) void gemm2_k(const unsigned short* __restrict__ Xb,
                                               const unsigned short* __restrict__ Wb,
                                               float* __restrict__ o2) {
  __shared__ unsigned short sW[128][40];
  __shared__ unsigned short sX[128][40];
  int t = threadIdx.x;
  int i0 = blockIdx.x * 128;
  int w = t >> 6, lane = t & 63;
  int wc = (w & 1) * 64, wn = (w >> 1) * 64;
  int l15 = lane & 15, g = lane >> 4;
  f32x4 acc[4][4];
#pragma unroll
  for (int a = 0; a < 4; ++a)
#pragma unroll
    for (int bq = 0; bq < 4; ++bq) acc[a][bq] = (f32x4)0.f;
  int sr = t & 127, sh = t >> 7;
  for (int kc = 0; kc < 8; ++kc) {
    int k0 = kc * 32;
    __syncthreads();
    {
      const uint4* gw = (const uint4*)&Wb[(size_t)sr * 256 + k0 + sh * 16];
      uint4 v0 = gw[0], v1 = gw[1];
      *(uint4*)&sW[sr][sh * 16] = v0;
      *(uint4*)&sW[sr][sh * 16 + 8] = v1;
      const uint4* gx = (const uint4*)&Xb[(size_t)(i0 + sr) * 256 + k0 + sh * 16];
      uint4 x0 = gx[0], x1 = gx[1];
      *(uint4*)&sX[sr][sh * 16] = x0;
      *(uint4*)&sX[sr][sh * 16 + 8] = x1;
    }
    __syncthreads();
    bf16x8 a[4], b[4];
#pragma unroll
    for (int tm = 0; tm < 4; ++tm)
      a[tm] = *(const bf16x8*)&sW[wc + tm * 16 + l15][g * 8];
#pragma unroll
    for (int tn = 0; tn < 4; ++tn)
      b[tn] = *(const bf16x8*)&sX[wn + tn * 16 + l15][g * 8];
#pragma unroll
    for (int tm = 0; tm < 4; ++tm)
#pragma unroll
      for (int tn = 0; tn < 4; ++tn)
        acc[tm][tn] = __builtin_amdgcn_mfma_f32_16x16x32_bf16(a[tm], b[tn], acc[tm][tn], 0, 0, 0);
  }
#pragma unroll
  for (int tm = 0; tm < 4; ++tm)
#pragma unroll
    for (int tn = 0; tn < 4; ++tn) {
      int c = wc + tm * 16 + g * 4;
      int n = i0 + wn + tn * 16 + l15;
      f32x4 v = acc[tm][tn];
      *(float4*)&o2[(size_t)n * 128 + c] = make_float4(v[0], v[1], v[2], v[3]);
    }
}

// final: out2T [i][128] + BN2 + relu -> d_out [B][128][16384] (transposed)
__global__ __launch_bounds__(256) void final_k(const float* __restrict__ o2,
                                               const float* __restrict__ A,
                                               const float* __restrict__ C,
                                               float* __restrict__ out) {
  __shared__ float tile[32][33];
  int b = blockIdx.z;
  int n0 = blockIdx.x * 32;
  int c0 = blockIdx.y * 32;
  int tx = threadIdx.x, ty = threadIdx.y;
  float a = A[c0 + tx], cc = C[c0 + tx];
  for (int r = ty; r < 32; r += 8) {
    float v = o2[(size_t)(b * 16384 + n0 + r) * 128 + c0 + tx];
    tile[r][tx] = fmaxf(fmaf(a, v, cc), 0.f);
  }
  __syncthreads();
  for (int r = ty; r < 32; r += 8)
    out[((size_t)(b * 128 + c0 + r)) * 16384 + n0 + tx] = tile[tx][r];
}

extern "C" void kernel_launch(void* const* d_in, const int* in_sizes, int n_in,
                              void* d_out, int out_size, void* d_ws, size_t ws_size,
                              hipStream_t stream) {
  const float* xyz1 = (const float*)d_in[0];
  const float* xyz2 = (const float*)d_in[1];
  const float* p1   = (const float*)d_in[2];
  const float* p2   = (const float*)d_in[3];
  const int*   idx1 = (const int*)d_in[4];
  const int*   idx2 = (const int*)d_in[5];
  const float* w1   = (const float*)d_in[6];
  // d_in[7]=b1, d_in[11]=b2: exactly absorbed by BN mean subtraction
  const float* g1   = (const float*)d_in[8];
  const float* be1  = (const float*)d_in[9];
  const float* w2   = (const float*)d_in[10];
  const float* g2   = (const float*)d_in[12];
  const float* be2  = (const float*)d_in[13];
  float* out = (float*)d_out;

  char* ws = (char*)d_ws;
  // idx3 0xC0000 | wgt 0xC0000 | X 48MB (h1bn 32MB aliases X after gemm1)
  // | h1T 32MB (p2t 16.8MB aliased; dead before gemm1 writes) | out2T 32MB
  // | w1bf | w2bf | part1 | part2 | params  => ~120MB
  int*            idx3 = (int*)(ws + 0x0);
  float*          wgt  = (float*)(ws + 0xC0000);
  unsigned short* X    = (unsigned short*)(ws + 0x180000);
  unsigned short* h1bn = (unsigned short*)(ws + 0x180000);      // alias X
  unsigned short* h1T  = (unsigned short*)(ws + 0x3180000);
  float*          p2t  = (float*)(ws + 0x3180000);              // alias h1T
  float*          o2   = (float*)(ws + 0x5180000);
  unsigned short* w1b  = (unsigned short*)(ws + 0x7180000);
  unsigned short* w2b  = (unsigned short*)(ws + 0x71B0000);
  float*          part1 = (float*)(ws + 0x71C0000);
  float*          part2 = (float*)(ws + 0x7240000);
  float*          a1   = (float*)(ws + 0x7280000);
  float*          c1   = a1 + 256;
  float*          a2   = c1 + 256;
  float*          c2   = a2 + 128;

  hipLaunchKernelGGL(transpose_k, dim3(128, 8, 4), dim3(32, 8), 0, stream, p2, p2t);
  hipLaunchKernelGGL(wcvt_k, dim3(512), dim3(256), 0, stream, w1, w2, w1b, w2b);
  hipLaunchKernelGGL(p1t_k, dim3(512, 4, 4), dim3(32, 8), 0, stream, p1, X);
  hipLaunchKernelGGL(knn_k, dim3(512), dim3(256), 0, stream,
                     xyz1, xyz2, idx1, idx2, idx3, wgt);
  hipLaunchKernelGGL(interp_k, dim3(512), dim3(256), 0, stream, p2t, idx3, wgt, X);
  hipLaunchKernelGGL(gemm1_k, dim3(512, 2), dim3(256), 0, stream, X, w1b, h1T);
  hipLaunchKernelGGL(bnstats1_k, dim3(256), dim3(256), 0, stream, h1T, part1);
  hipLaunchKernelGGL((bnfold_k<256>), dim3(1), dim3(256), 0, stream, part1, g1, be1, a1, c1);
  hipLaunchKernelGGL(bnapply1_k, dim3(8192), dim3(256), 0, stream, h1T, a1, c1, h1bn);
  hipLaunchKernelGGL(gemm2_k, dim3(512), dim3(256), 0, stream, h1bn, w2b, o2);
  hipLaunchKernelGGL(bnstats2_k, dim3(256), dim3(256), 0, stream, o2, part2);
  hipLaunchKernelGGL((bnfold_k<128>), dim3(1), dim3(256), 0, stream, part2, g2, be2, a2, c2);
  hipLaunchKernelGGL(final_k, dim3(512, 4, 4), dim3(32, 8), 0, stream, o2, a2, c2, out);
}

// Round 6
// 262.149 us; speedup vs baseline: 2.7600x; 1.1871x over previous
//
#include <hip/hip_runtime.h>
#include <hip/hip_bf16.h>

#define INF_F (__builtin_inff())

typedef __attribute__((ext_vector_type(8))) short bf16x8;
typedef __attribute__((ext_vector_type(4))) float f32x4;

__device__ __forceinline__ unsigned short f2bf(float f) {
  __hip_bfloat16 h = __float2bfloat16(f);
  return __builtin_bit_cast(unsigned short, h);
}
__device__ __forceinline__ float bf2f(unsigned short u) {
  return __uint_as_float((unsigned)u << 16);
}

// ---------------------------------------------------------------------------
// B=4, N=16384, S=4096, D1=128, D2=256, MLP=(256,128). M = B*N = 65536.
// X: [65536][384] bf16 (cols 0..127 = points1^T, 128..383 = interp)
// h1T: [65536][256] bf16 ; out2T: [65536][128] fp32.
// GEMMs: D[c][n] = W[c][k] * X[n][k] via mfma_f32_16x16x32_bf16.
// ---------------------------------------------------------------------------

// points2 [B][256][4096] -> p2t [B][4096][256] fp32 (coalesced gather rows)
__global__ __launch_bounds__(256) void transpose_k(const float* __restrict__ in,
                                                   float* __restrict__ out) {
  __shared__ float tile[32][33];
  int b = blockIdx.z;
  int s0 = blockIdx.x * 32;
  int k0 = blockIdx.y * 32;
  int tx = threadIdx.x, ty = threadIdx.y;  // 32 x 8
  const float* src = in + ((size_t)b * 256 + k0) * 4096 + s0;
  for (int r = ty; r < 32; r += 8) tile[r][tx] = src[(size_t)r * 4096 + tx];
  __syncthreads();
  float* dst = out + ((size_t)b * 4096 + s0) * 256 + k0;
  for (int r = ty; r < 32; r += 8) dst[(size_t)r * 256 + tx] = tile[tx][r];
}

// p1 [B][128][16384] fp32 -> X[b*16384+n][0..127] bf16 (transposed)
__global__ __launch_bounds__(256) void p1t_k(const float* __restrict__ p1,
                                             unsigned short* __restrict__ X) {
  __shared__ float tile[32][33];
  int b = blockIdx.z;
  int n0 = blockIdx.x * 32;
  int c0 = blockIdx.y * 32;
  int tx = threadIdx.x, ty = threadIdx.y;
  const float* src = p1 + ((size_t)b * 128 + c0) * 16384 + n0;
  for (int r = ty; r < 32; r += 8) tile[r][tx] = src[(size_t)r * 16384 + tx];
  __syncthreads();
  for (int r = ty; r < 32; r += 8)
    X[((size_t)(b * 16384 + n0 + r)) * 384 + c0 + tx] = f2bf(tile[tx][r]);
}

// w1 [256][384], w2 [128][256] fp32 -> bf16 copies (same layout)
__global__ __launch_bounds__(256) void wcvt_k(const float* __restrict__ w1,
                                              const float* __restrict__ w2,
                                              unsigned short* __restrict__ w1b,
                                              unsigned short* __restrict__ w2b) {
  int id = blockIdx.x * 256 + threadIdx.x;
  if (id < 98304) w1b[id] = f2bf(w1[id]);
  else w2b[id - 98304] = f2bf(w2[id - 98304]);
}

// 3-NN stage 1: per (128-query chunk, S-half) partial top-3.
// grid 1024 = 512 n-chunks x 2 S-halves; 256 thr = 128 q x 2 S-quarters.
// Validity (idx1==idx2) folded into staged |p|^2 (w=3e38 if source batch-id
// != block's common id): removes per-pair sId read+select. Per-thread slow
// path preserves exact semantics if a query's id differs from common (never
// on this data). Insert is branchy: common case = read+4fmaf+1cmp only.
__global__ __launch_bounds__(256) void knn_k(const float* __restrict__ xyz1,
                                             const float* __restrict__ xyz2,
                                             const int* __restrict__ idx1,
                                             const int* __restrict__ idx2,
                                             float* __restrict__ rec) {
  __shared__ float4 sP[2048];  // 32KB
  int bid = blockIdx.x;
  int nchunk = bid >> 1, shalf = bid & 1;
  int b = nchunk >> 7;
  int n0 = (nchunk & 127) * 128;
  int t = threadIdx.x;
  int q = t & 127, sp = t >> 7;
  int n = n0 + q;
  int common = idx1[b * 16384 + n0];
  int sbase = shalf << 11;
  for (int s = t; s < 2048; s += 256) {
    int gs = sbase + s;
    float x = xyz2[(b * 3 + 0) * 4096 + gs];
    float y = xyz2[(b * 3 + 1) * 4096 + gs];
    float z = xyz2[(b * 3 + 2) * 4096 + gs];
    float w = fmaf(x, x, fmaf(y, y, z * z));
    int sid = idx2[b * 4096 + gs];
    w = (sid == common) ? w : 3e38f;  // invalid -> d ~ 3e38 > BIG -> weight 0
    sP[s] = make_float4(x, y, z, w);
  }
  __syncthreads();
  float px = xyz1[(b * 3 + 0) * 16384 + n];
  float py = xyz1[(b * 3 + 1) * 16384 + n];
  float pz = xyz1[(b * 3 + 2) * 16384 + n];
  int myid = idx1[b * 16384 + n];
  float pn = fmaf(px, px, fmaf(py, py, pz * pz));
  float e0 = INF_F, e1 = INF_F, e2 = INF_F;
  int j0 = 0, j1 = 0, j2 = 0;
  int sBeg = sp << 10, sEnd = sBeg + 1024;
#pragma unroll 4
  for (int s = sBeg; s < sEnd; ++s) {
    float4 p = sP[s];  // wave-uniform addr -> LDS broadcast, conflict-free
    float dot = fmaf(px, p.x, fmaf(py, p.y, pz * p.z));
    float d = fmaf(-2.f, dot, pn + p.w);  // same formula as ref
    if (d < e2) {  // rare past warmup; strict < + ascending s = top_k ties
      int sj = sbase + s;
      bool l0 = d < e0, l1 = d < e1;
      e2 = l1 ? e1 : d;
      j2 = l1 ? j1 : sj;
      e1 = l0 ? e0 : (l1 ? d : e1);
      j1 = l0 ? j0 : (l1 ? sj : j1);
      e0 = l0 ? d : e0;
      j0 = l0 ? sj : j0;
    }
  }
  if (__builtin_expect(myid != common, 0)) {  // exact general-idx fallback
    e0 = e1 = e2 = INF_F; j0 = j1 = j2 = 0;
    for (int s = sBeg; s < sEnd; ++s) {
      int gs = sbase + s;
      float x = xyz2[(b * 3 + 0) * 4096 + gs];
      float y = xyz2[(b * 3 + 1) * 4096 + gs];
      float z = xyz2[(b * 3 + 2) * 4096 + gs];
      float w = fmaf(x, x, fmaf(y, y, z * z));
      float dot = fmaf(px, x, fmaf(py, y, pz * z));
      float d = fmaf(-2.f, dot, pn + w);
      d = (idx2[b * 4096 + gs] == myid) ? d : INF_F;
      if (d < e2) {
        bool l0 = d < e0, l1 = d < e1;
        e2 = l1 ? e1 : d; j2 = l1 ? j1 : gs;
        e1 = l0 ? e0 : (l1 ? d : e1); j1 = l0 ? j0 : (l1 ? gs : j1);
        e0 = l0 ? d : e0; j0 = l0 ? gs : j0;
      }
    }
  }
  __syncthreads();
  float* sf = (float*)sP;
  int* si = (int*)sP;
  if (sp == 1) {  // publish in stride-1 planes (conflict-free)
    sf[0 * 128 + q] = e0; sf[1 * 128 + q] = e1; sf[2 * 128 + q] = e2;
    si[3 * 128 + q] = j0; si[4 * 128 + q] = j1; si[5 * 128 + q] = j2;
  }
  __syncthreads();
  if (t < 128) {  // sp0 regs cover lower s; partner higher s: lex (d,idx)
#pragma unroll
    for (int w = 0; w < 3; ++w) {
      float d = sf[w * 128 + t];
      int sj = si[(w + 3) * 128 + t];
      bool l0 = (d < e0) || (d == e0 && sj < j0);
      bool l1 = (d < e1) || (d == e1 && sj < j1);
      bool l2 = (d < e2) || (d == e2 && sj < j2);
      e2 = l1 ? e1 : (l2 ? d : e2);
      j2 = l1 ? j1 : (l2 ? sj : j2);
      e1 = l0 ? e0 : (l1 ? d : e1);
      j1 = l0 ? j0 : (l1 ? sj : j1);
      e0 = l0 ? d : e0;
      j0 = l0 ? sj : j0;
    }
    float* r = &rec[(((size_t)nchunk * 128 + t) * 2 + shalf) * 6];
    r[0] = e0; r[1] = e1; r[2] = e2;
    ((int*)r)[3] = j0; ((int*)r)[4] = j1; ((int*)r)[5] = j2;
  }
}

// 3-NN stage 2: merge the two S-half records, compute weights. 256 x 256.
__global__ __launch_bounds__(256) void knnmerge_k(const float* __restrict__ rec,
                                                  int* __restrict__ idx3,
                                                  float* __restrict__ wgt) {
  int i = blockIdx.x * 256 + threadIdx.x;  // 65536 queries
  const float* rA = &rec[(size_t)i * 12];
  const int* iA = (const int*)rA;
  float e0 = rA[0], e1 = rA[1], e2 = rA[2];
  int j0 = iA[3], j1 = iA[4], j2 = iA[5];
#pragma unroll
  for (int w = 0; w < 3; ++w) {  // half1 indices all > half0: lex (d,idx)
    float d = rA[6 + w];
    int sj = iA[9 + w];
    bool l0 = (d < e0) || (d == e0 && sj < j0);
    bool l1 = (d < e1) || (d == e1 && sj < j1);
    bool l2 = (d < e2) || (d == e2 && sj < j2);
    e2 = l1 ? e1 : (l2 ? d : e2);
    j2 = l1 ? j1 : (l2 ? sj : j2);
    e1 = l0 ? e0 : (l1 ? d : e1);
    j1 = l0 ? j0 : (l1 ? sj : j1);
    e0 = l0 ? d : e0;
    j0 = l0 ? sj : j0;
  }
  float r0 = 1.f / (e0 + 1e-8f);
  float r1 = 1.f / (e1 + 1e-8f);
  float r2 = 1.f / (e2 + 1e-8f);
  float rs = r0 + r1 + r2;
  float w0 = (e0 > 1e8f) ? 0.f : r0 / rs;  // ref: where(d3>BIG,0)+nan_to_num
  float w1 = (e1 > 1e8f) ? 0.f : r1 / rs;
  float w2 = (e2 > 1e8f) ? 0.f : r2 / rs;
  idx3[(size_t)i * 3 + 0] = j0; idx3[(size_t)i * 3 + 1] = j1; idx3[(size_t)i * 3 + 2] = j2;
  wgt[(size_t)i * 3 + 0] = w0;  wgt[(size_t)i * 3 + 1] = w1;  wgt[(size_t)i * 3 + 2] = w2;
}

// interp -> X[i][128+k] bf16
__global__ __launch_bounds__(256) void interp_k(const float* __restrict__ p2t,
                                                const int* __restrict__ idx3,
                                                const float* __restrict__ wgt,
                                                unsigned short* __restrict__ X) {
  int i0 = blockIdx.x * 128;
  int b = i0 >> 14;
  int k = threadIdx.x;
  const float* base = p2t + (size_t)b * 4096 * 256;
#pragma unroll 2
  for (int ii = 0; ii < 128; ++ii) {
    int i = i0 + ii;
    int id0 = idx3[i * 3 + 0], id1 = idx3[i * 3 + 1], id2 = idx3[i * 3 + 2];
    float w0 = wgt[i * 3 + 0], w1v = wgt[i * 3 + 1], w2v = wgt[i * 3 + 2];
    float v = w0 * base[id0 * 256 + k];
    v = fmaf(w1v, base[id1 * 256 + k], v);
    v = fmaf(w2v, base[id2 * 256 + k], v);
    X[(size_t)i * 384 + 128 + k] = f2bf(v);
  }
}

// GEMM1 (MFMA): h1T[n][c] = sum_k w1[c][k] X[n][k]. 128x128 tile, BK=32,
// K=384. grid (512, 2).
__global__ __launch_bounds__(256) void gemm1_k(const unsigned short* __restrict__ X,
                                               const unsigned short* __restrict__ Wb,
                                               unsigned short* __restrict__ h1T) {
  __shared__ unsigned short sW[128][40];
  __shared__ unsigned short sX[128][40];
  int t = threadIdx.x;
  int i0 = blockIdx.x * 128;
  int c0 = blockIdx.y * 128;
  int w = t >> 6, lane = t & 63;
  int wc = (w & 1) * 64, wn = (w >> 1) * 64;
  int l15 = lane & 15, g = lane >> 4;
  f32x4 acc[4][4];
#pragma unroll
  for (int a = 0; a < 4; ++a)
#pragma unroll
    for (int bq = 0; bq < 4; ++bq) acc[a][bq] = (f32x4)0.f;
  int sr = t & 127, sh = t >> 7;
  for (int kc = 0; kc < 12; ++kc) {
    int k0 = kc * 32;
    __syncthreads();
    {
      const uint4* gw = (const uint4*)&Wb[(size_t)(c0 + sr) * 384 + k0 + sh * 16];
      uint4 v0 = gw[0], v1 = gw[1];
      *(uint4*)&sW[sr][sh * 16] = v0;
      *(uint4*)&sW[sr][sh * 16 + 8] = v1;
      const uint4* gx = (const uint4*)&X[(size_t)(i0 + sr) * 384 + k0 + sh * 16];
      uint4 x0 = gx[0], x1 = gx[1];
      *(uint4*)&sX[sr][sh * 16] = x0;
      *(uint4*)&sX[sr][sh * 16 + 8] = x1;
    }
    __syncthreads();
    bf16x8 a[4], b[4];
#pragma unroll
    for (int tm = 0; tm < 4; ++tm)
      a[tm] = *(const bf16x8*)&sW[wc + tm * 16 + l15][g * 8];
#pragma unroll
    for (int tn = 0; tn < 4; ++tn)
      b[tn] = *(const bf16x8*)&sX[wn + tn * 16 + l15][g * 8];
#pragma unroll
    for (int tm = 0; tm < 4; ++tm)
#pragma unroll
      for (int tn = 0; tn < 4; ++tn)
        acc[tm][tn] = __builtin_amdgcn_mfma_f32_16x16x32_bf16(a[tm], b[tn], acc[tm][tn], 0, 0, 0);
  }
#pragma unroll
  for (int tm = 0; tm < 4; ++tm)
#pragma unroll
    for (int tn = 0; tn < 4; ++tn) {
      int c = c0 + wc + tm * 16 + g * 4;
      int n = i0 + wn + tn * 16 + l15;
      f32x4 v = acc[tm][tn];
      ushort4 o;
      o.x = f2bf(v[0]); o.y = f2bf(v[1]); o.z = f2bf(v[2]); o.w = f2bf(v[3]);
      *(ushort4*)&h1T[(size_t)n * 256 + c] = o;
    }
}

// BN1 stats over h1T bf16 [65536][256]
__global__ __launch_bounds__(256) void bnstats1_k(const unsigned short* __restrict__ h,
                                                  float* __restrict__ part) {
  int t = threadIdx.x, q = t & 63, ro = t >> 6;
  int r0 = blockIdx.x * 256;
  float s0 = 0, s1 = 0, s2 = 0, s3 = 0, q0 = 0, q1 = 0, q2 = 0, q3 = 0;
  for (int it = 0; it < 64; ++it) {
    size_t r = r0 + it * 4 + ro;
    ushort4 v = *(const ushort4*)&h[r * 256 + q * 4];
    float f0 = bf2f(v.x), f1 = bf2f(v.y), f2 = bf2f(v.z), f3 = bf2f(v.w);
    s0 += f0; q0 += f0 * f0;
    s1 += f1; q1 += f1 * f1;
    s2 += f2; q2 += f2 * f2;
    s3 += f3; q3 += f3 * f3;
  }
  __shared__ float sm[256][8];
  sm[t][0] = s0; sm[t][1] = s1; sm[t][2] = s2; sm[t][3] = s3;
  sm[t][4] = q0; sm[t][5] = q1; sm[t][6] = q2; sm[t][7] = q3;
  __syncthreads();
  if (t < 64) {
#pragma unroll
    for (int j = 1; j < 4; ++j)
#pragma unroll
      for (int e = 0; e < 8; ++e) sm[t][e] += sm[t + 64 * j][e];
#pragma unroll
    for (int i = 0; i < 4; ++i) {
      part[((size_t)blockIdx.x * 256 + t * 4 + i) * 2 + 0] = sm[t][i];
      part[((size_t)blockIdx.x * 256 + t * 4 + i) * 2 + 1] = sm[t][4 + i];
    }
  }
}

// BN2 stats over out2T fp32 [65536][128]
__global__ __launch_bounds__(256) void bnstats2_k(const float* __restrict__ o2,
                                                  float* __restrict__ part) {
  int t = threadIdx.x, q = t & 31, ro = t >> 5;
  int r0 = blockIdx.x * 256;
  float s0 = 0, s1 = 0, s2 = 0, s3 = 0, q0 = 0, q1 = 0, q2 = 0, q3 = 0;
  for (int it = 0; it < 32; ++it) {
    size_t r = r0 + it * 8 + ro;
    float4 v = *(const float4*)&o2[r * 128 + q * 4];
    s0 += v.x; q0 += v.x * v.x;
    s1 += v.y; q1 += v.y * v.y;
    s2 += v.z; q2 += v.z * v.z;
    s3 += v.w; q3 += v.w * v.w;
  }
  __shared__ float sm[256][8];
  sm[t][0] = s0; sm[t][1] = s1; sm[t][2] = s2; sm[t][3] = s3;
  sm[t][4] = q0; sm[t][5] = q1; sm[t][6] = q2; sm[t][7] = q3;
  __syncthreads();
  if (t < 32) {
#pragma unroll
    for (int j = 1; j < 8; ++j)
#pragma unroll
      for (int e = 0; e < 8; ++e) sm[t][e] += sm[t + 32 * j][e];
#pragma unroll
    for (int i = 0; i < 4; ++i) {
      part[((size_t)blockIdx.x * 128 + t * 4 + i) * 2 + 0] = sm[t][i];
      part[((size_t)blockIdx.x * 128 + t * 4 + i) * 2 + 1] = sm[t][4 + i];
    }
  }
}

// fold partials -> per-channel a*x + c
template <int C>
__global__ __launch_bounds__(256) void bnfold_k(const float* __restrict__ part,
                                                const float* __restrict__ g,
                                                const float* __restrict__ be,
                                                float* __restrict__ A,
                                                float* __restrict__ Cc) {
  int c = threadIdx.x;
  if (c >= C) return;
  float s1 = 0.f, s2 = 0.f;
  for (int b = 0; b < 256; ++b) {
    s1 += part[((size_t)b * C + c) * 2 + 0];
    s2 += part[((size_t)b * C + c) * 2 + 1];
  }
  float mean = s1 * (1.f / 65536.f);
  float var = s2 * (1.f / 65536.f) - mean * mean;  // biased, as torch BN
  float a = g[c] * rsqrtf(var + 1e-5f);
  A[c] = a;
  Cc[c] = be[c] - mean * a;
}

// h1bn[i][c] = bf16(relu(a1[c]*h1T[i][c] + c1[c]))
__global__ __launch_bounds__(256) void bnapply1_k(const unsigned short* __restrict__ h,
                                                  const float* __restrict__ A,
                                                  const float* __restrict__ C,
                                                  unsigned short* __restrict__ o) {
  size_t idx = ((size_t)blockIdx.x * 256 + threadIdx.x) * 8;
  int c = (int)(idx & 255);
  uint4 v = *(const uint4*)&h[idx];
  float4 a0 = *(const float4*)&A[c], a1 = *(const float4*)&A[c + 4];
  float4 c0 = *(const float4*)&C[c], c1 = *(const float4*)&C[c + 4];
  unsigned r[4] = {v.x, v.y, v.z, v.w};
  float av[8] = {a0.x, a0.y, a0.z, a0.w, a1.x, a1.y, a1.z, a1.w};
  float cv[8] = {c0.x, c0.y, c0.z, c0.w, c1.x, c1.y, c1.z, c1.w};
  unsigned w[4];
#pragma unroll
  for (int e = 0; e < 4; ++e) {
    float f0 = bf2f((unsigned short)(r[e] & 0xFFFFu));
    float f1 = bf2f((unsigned short)(r[e] >> 16));
    f0 = fmaxf(fmaf(av[2 * e], f0, cv[2 * e]), 0.f);
    f1 = fmaxf(fmaf(av[2 * e + 1], f1, cv[2 * e + 1]), 0.f);
    w[e] = (unsigned)f2bf(f0) | ((unsigned)f2bf(f1) << 16);
  }
  uint4 ov = {w[0], w[1], w[2], w[3]};
  *(uint4*)&o[idx] = ov;
}

// GEMM2 (MFMA): out2T[n][c2] = sum_k w2[c2][k] h1bn[n][k]. K=256. grid (512).
__global__ __launch_bounds__(256) void gemm2_k(const unsigned short* __restrict__ Xb,
                                               const unsigned short* __restrict__ Wb,
                                               float* __restrict__ o2) {
  __shared__ unsigned short sW[128][40];
  __shared__ unsigned short sX[128][40];
  int t = threadIdx.x;
  int i0 = blockIdx.x * 128;
  int w = t >> 6, lane = t & 63;
  int wc = (w & 1) * 64, wn = (w >> 1) * 64;
  int l15 = lane & 15, g = lane >> 4;
  f32x4 acc[4][4];
#pragma unroll
  for (int a = 0; a < 4; ++a)
#pragma unroll
    for (int bq = 0; bq < 4; ++bq) acc[a][bq] = (f32x4)0.f;
  int sr = t & 127, sh = t >> 7;
  for (int kc = 0; kc < 8; ++kc) {
    int k0 = kc * 32;
    __syncthreads();
    {
      const uint4* gw = (const uint4*)&Wb[(size_t)sr * 256 + k0 + sh * 16];
      uint4 v0 = gw[0], v1 = gw[1];
      *(uint4*)&sW[sr][sh * 16] = v0;
      *(uint4*)&sW[sr][sh * 16 + 8] = v1;
      const uint4* gx = (const uint4*)&Xb[(size_t)(i0 + sr) * 256 + k0 + sh * 16];
      uint4 x0 = gx[0], x1 = gx[1];
      *(uint4*)&sX[sr][sh * 16] = x0;
      *(uint4*)&sX[sr][sh * 16 + 8] = x1;
    }
    __syncthreads();
    bf16x8 a[4], b[4];
#pragma unroll
    for (int tm = 0; tm < 4; ++tm)
      a[tm] = *(const bf16x8*)&sW[wc + tm * 16 + l15][g * 8];
#pragma unroll
    for (int tn = 0; tn < 4; ++tn)
      b[tn] = *(const bf16x8*)&sX[wn + tn * 16 + l15][g * 8];
#pragma unroll
    for (int tm = 0; tm < 4; ++tm)
#pragma unroll
      for (int tn = 0; tn < 4; ++tn)
        acc[tm][tn] = __builtin_amdgcn_mfma_f32_16x16x32_bf16(a[tm], b[tn], acc[tm][tn], 0, 0, 0);
  }
#pragma unroll
  for (int tm = 0; tm < 4; ++tm)
#pragma unroll
    for (int tn = 0; tn < 4; ++tn) {
      int c = wc + tm * 16 + g * 4;
      int n = i0 + wn + tn * 16 + l15;
      f32x4 v = acc[tm][tn];
      *(float4*)&o2[(size_t)n * 128 + c] = make_float4(v[0], v[1], v[2], v[3]);
    }
}

// final: out2T [i][128] + BN2 + relu -> d_out [B][128][16384] (transposed)
__global__ __launch_bounds__(256) void final_k(const float* __restrict__ o2,
                                               const float* __restrict__ A,
                                               const float* __restrict__ C,
                                               float* __restrict__ out) {
  __shared__ float tile[32][33];
  int b = blockIdx.z;
  int n0 = blockIdx.x * 32;
  int c0 = blockIdx.y * 32;
  int tx = threadIdx.x, ty = threadIdx.y;
  float a = A[c0 + tx], cc = C[c0 + tx];
  for (int r = ty; r < 32; r += 8) {
    float v = o2[(size_t)(b * 16384 + n0 + r) * 128 + c0 + tx];
    tile[r][tx] = fmaxf(fmaf(a, v, cc), 0.f);
  }
  __syncthreads();
  for (int r = ty; r < 32; r += 8)
    out[((size_t)(b * 128 + c0 + r)) * 16384 + n0 + tx] = tile[tx][r];
}

extern "C" void kernel_launch(void* const* d_in, const int* in_sizes, int n_in,
                              void* d_out, int out_size, void* d_ws, size_t ws_size,
                              hipStream_t stream) {
  const float* xyz1 = (const float*)d_in[0];
  const float* xyz2 = (const float*)d_in[1];
  const float* p1   = (const float*)d_in[2];
  const float* p2   = (const float*)d_in[3];
  const int*   idx1 = (const int*)d_in[4];
  const int*   idx2 = (const int*)d_in[5];
  const float* w1   = (const float*)d_in[6];
  // d_in[7]=b1, d_in[11]=b2: exactly absorbed by BN mean subtraction
  const float* g1   = (const float*)d_in[8];
  const float* be1  = (const float*)d_in[9];
  const float* w2   = (const float*)d_in[10];
  const float* g2   = (const float*)d_in[12];
  const float* be2  = (const float*)d_in[13];
  float* out = (float*)d_out;

  char* ws = (char*)d_ws;
  int*            idx3 = (int*)(ws + 0x0);                      // 0.75MB
  float*          wgt  = (float*)(ws + 0xC0000);                // 0.75MB
  float*          rec  = (float*)(ws + 0x180000);               // 3MB
  unsigned short* X    = (unsigned short*)(ws + 0x480000);      // 48MB
  unsigned short* h1bn = (unsigned short*)(ws + 0x480000);      // alias X
  unsigned short* h1T  = (unsigned short*)(ws + 0x3480000);     // 32MB
  float*          p2t  = (float*)(ws + 0x3480000);              // alias h1T
  float*          o2   = (float*)(ws + 0x5480000);              // 32MB
  unsigned short* w1b  = (unsigned short*)(ws + 0x7480000);
  unsigned short* w2b  = (unsigned short*)(ws + 0x74B0000);
  float*          part1 = (float*)(ws + 0x74C0000);
  float*          part2 = (float*)(ws + 0x7540000);
  float*          a1   = (float*)(ws + 0x7580000);
  float*          c1   = a1 + 256;
  float*          a2   = c1 + 256;
  float*          c2   = a2 + 128;

  hipLaunchKernelGGL(transpose_k, dim3(128, 8, 4), dim3(32, 8), 0, stream, p2, p2t);
  hipLaunchKernelGGL(wcvt_k, dim3(512), dim3(256), 0, stream, w1, w2, w1b, w2b);
  hipLaunchKernelGGL(p1t_k, dim3(512, 4, 4), dim3(32, 8), 0, stream, p1, X);
  hipLaunchKernelGGL(knn_k, dim3(1024), dim3(256), 0, stream,
                     xyz1, xyz2, idx1, idx2, rec);
  hipLaunchKernelGGL(knnmerge_k, dim3(256), dim3(256), 0, stream, rec, idx3, wgt);
  hipLaunchKernelGGL(interp_k, dim3(512), dim3(256), 0, stream, p2t, idx3, wgt, X);
  hipLaunchKernelGGL(gemm1_k, dim3(512, 2), dim3(256), 0, stream, X, w1b, h1T);
  hipLaunchKernelGGL(bnstats1_k, dim3(256), dim3(256), 0, stream, h1T, part1);
  hipLaunchKernelGGL((bnfold_k<256>), dim3(1), dim3(256), 0, stream, part1, g1, be1, a1, c1);
  hipLaunchKernelGGL(bnapply1_k, dim3(8192), dim3(256), 0, stream, h1T, a1, c1, h1bn);
  hipLaunchKernelGGL(gemm2_k, dim3(512), dim3(256), 0, stream, h1bn, w2b, o2);
  hipLaunchKernelGGL(bnstats2_k, dim3(256), dim3(256), 0, stream, o2, part2);
  hipLaunchKernelGGL((bnfold_k<128>), dim3(1), dim3(256), 0, stream, part2, g2, be2, a2, c2);
  hipLaunchKernelGGL(final_k, dim3(512, 4, 4), dim3(32, 8), 0, stream, o2, a2, c2, out);
}